// Round 3
// baseline (372.797 us; speedup 1.0000x reference)
//
#include <hip/hip_runtime.h>
#include <stdint.h>

#define M_DIM 8192
#define N_DIM 8192
#define K_DIM 1024

typedef int int4v __attribute__((ext_vector_type(4)));

// ---- async global->LDS, 16B per lane ----
__device__ __forceinline__ void gload16(const char* g, char* l) {
    __builtin_amdgcn_global_load_lds(
        (__attribute__((address_space(1))) void*)(void*)const_cast<char*>(g),
        (__attribute__((address_space(3))) void*)l,
        16, 0, 0);
}

__device__ __forceinline__ int sat8(int v) {
    v = v > 127 ? 127 : v;
    v = v < -128 ? -128 : v;
    return v;
}

// ---- fused pack: blocks [0,8192) pack A; blocks [8192,10240) transpose-pack B ----
__global__ __launch_bounds__(256) void pack_ab_kernel(const int* __restrict__ a,
                                                      const int* __restrict__ b,
                                                      int* __restrict__ outA,
                                                      char* __restrict__ outB) {
    __shared__ char tile[64][68];               // used by B-blocks only
    const int t = threadIdx.x;
    if (blockIdx.x < 8192) {
        // pack a: int32 [M][K] -> int8 [M][K], 4 elems/thread, coalesced
        int i = blockIdx.x * 256 + t;
        int4 v = ((const int4*)a)[i];
        outA[i] = (v.x & 0xff) | ((v.y & 0xff) << 8) |
                  ((v.z & 0xff) << 16) | ((v.w & 0xff) << 24);
        return;
    }
    // pack b: int32 [K][N] -> int8 [N][K] (transpose via LDS tile)
    const int bx = blockIdx.x - 8192;           // 0..2047
    const int n0 = (bx & 127) * 64;
    const int k0 = (bx >> 7) * 64;
    const int tr  = t >> 4;                     // 0..15
    const int tc4 = (t & 15) << 2;              // 0,4,..,60
#pragma unroll
    for (int j = 0; j < 4; ++j) {
        int row = tr + j * 16;                  // k within tile
        int4 v = *(const int4*)&b[(size_t)(k0 + row) * N_DIM + n0 + tc4];
        tile[row][tc4 + 0] = (char)v.x;
        tile[row][tc4 + 1] = (char)v.y;
        tile[row][tc4 + 2] = (char)v.z;
        tile[row][tc4 + 3] = (char)v.w;
    }
    __syncthreads();
#pragma unroll
    for (int j = 0; j < 4; ++j) {
        int n = tr + j * 16;                    // n within tile
        int pk = (tile[tc4 + 0][n] & 0xff) |
                 ((tile[tc4 + 1][n] & 0xff) << 8) |
                 ((tile[tc4 + 2][n] & 0xff) << 16) |
                 ((tile[tc4 + 3][n] & 0xff) << 24);
        *(int*)&outB[(size_t)(n0 + n) * K_DIM + k0 + tc4] = pk;
    }
}

// ---- GEMM: 128x128 tile, BK=64, triple-buffered LDS, counted vmcnt(4) ----
// R2 post-mortem: T2 swizzle alone was null (regime gate: 2-phase critical path
// is the stage->vmcnt(0)->barrier drain, not LDS reads). This round removes the
// drain: tiles staged 2 K-steps ahead into a 3-slot LDS ring, one raw s_barrier
// per K-step, s_waitcnt vmcnt(4) (NEVER 0 in the loop; 4 = loads/thread/tile,
// retires exactly the tile needed next step). No __syncthreads in the loop (it
// would drain vmcnt to 0). Slot lifecycle: tile t in slot t%3, staged at t-2,
// read at t (reads retired before t's end-barrier via lgkm-before-MFMA),
// overwritten at t+1 after that barrier. Tail: stage index clamps to 15 -> a
// few redundant L2-hot loads into dead slots, race-free.
// Math identical to the verified R0/R2 kernel (same fragment layout + swizzle).
__global__ __launch_bounds__(256) void gemm_i8_kernel(const char* __restrict__ A8,
                                                      const char* __restrict__ B8,
                                                      int* __restrict__ C) {
    __shared__ __align__(16) char As[3][128][64];   // 3 x 8KB K64-slices
    __shared__ __align__(16) char Bs[3][128][64];

    const int t    = threadIdx.x;
    const int bn   = blockIdx.x;
    const int bm   = blockIdx.y;
    const int lane = t & 63;
    const int wave = t >> 6;
    const int wm   = wave >> 1;                  // 2x2 wave grid, 64x64 per wave
    const int wn   = wave & 1;
    const int quad = lane >> 4;
    const int l16  = lane & 15;

    // staging: 2 x 16B chunks per operand per tile per thread (128 rows x 64B)
    // T2 swizzle (rule 21): source chunk = (t&3)^((row>>1)&3), LDS dest linear.
    const int sr   = t >> 2;                     // row 0..63 (i=1 adds 64)
    const int swzc = (((t & 3) ^ ((t >> 3) & 3)) << 4);
    const char* aSrc = A8 + (size_t)(bm * 128) * K_DIM + (size_t)sr * K_DIM + swzc;
    const char* bSrc = B8 + (size_t)(bn * 128) * K_DIM + (size_t)sr * K_DIM + swzc;
    // swizzled read chunk (per-lane constant; frag rows are multiples of 16)
    const int laneByte = ((quad ^ ((l16 >> 1) & 3)) << 4);
    const int aRow = wm * 64 + l16;
    const int bRow = wn * 64 + l16;

    int4v acc[4][4] = {};

#define STAGE(TILE, SLOT) do {                                                  \
    const int kOff_ = (TILE) * 64;                                              \
    gload16(aSrc + kOff_,                        &As[SLOT][0][0] + t * 16);     \
    gload16(aSrc + (size_t)64 * K_DIM + kOff_,   &As[SLOT][0][0] + (t + 256) * 16); \
    gload16(bSrc + kOff_,                        &Bs[SLOT][0][0] + t * 16);     \
    gload16(bSrc + (size_t)64 * K_DIM + kOff_,   &Bs[SLOT][0][0] + (t + 256) * 16); \
} while (0)

    // prologue: tiles 0,1 in flight; retire tile 0 (oldest 4 loads), publish
    STAGE(0, 0);
    STAGE(1, 1);
    asm volatile("s_waitcnt vmcnt(4)" ::: "memory");
    __builtin_amdgcn_s_barrier();
    __builtin_amdgcn_sched_barrier(0);

#pragma unroll
    for (int kt = 0; kt < K_DIM / 64; ++kt) {
        const int cur  = kt % 3;
        const int slot = (kt + 2) % 3;
        const int tile = (kt + 2 < K_DIM / 64) ? kt + 2 : K_DIM / 64 - 1;

        int4v af[4], bf[4];
#pragma unroll
        for (int mi = 0; mi < 4; ++mi)
            af[mi] = *(const int4v*)&As[cur][aRow + mi * 16][laneByte];
#pragma unroll
        for (int ni = 0; ni < 4; ++ni)
            bf[ni] = *(const int4v*)&Bs[cur][bRow + ni * 16][laneByte];

        STAGE(tile, slot);                       // lands in 2 K-steps

        __builtin_amdgcn_s_setprio(1);
#pragma unroll
        for (int mi = 0; mi < 4; ++mi)
#pragma unroll
            for (int ni = 0; ni < 4; ++ni)
                acc[mi][ni] = __builtin_amdgcn_mfma_i32_16x16x64_i8(
                    af[mi], bf[ni], acc[mi][ni], 0, 0, 0);
        __builtin_amdgcn_s_setprio(0);

        asm volatile("s_waitcnt vmcnt(4)" ::: "memory");  // next tile resident
        __builtin_amdgcn_s_barrier();
        __builtin_amdgcn_sched_barrier(0);
    }
#undef STAGE

    // don't exit with outstanding LDS-DMA (redundant tail stages)
    asm volatile("s_waitcnt vmcnt(0)" ::: "memory");

    // epilogue: C/D layout col=lane&15, row=4*quad+reg; saturate, store int32
    const int mBase = bm * 128 + wm * 64;
    const int nBase = bn * 128 + wn * 64;
#pragma unroll
    for (int mi = 0; mi < 4; ++mi) {
#pragma unroll
        for (int ni = 0; ni < 4; ++ni) {
            const int col = nBase + ni * 16 + l16;
#pragma unroll
            for (int r = 0; r < 4; ++r) {
                const int row = mBase + mi * 16 + quad * 4 + r;
                C[(size_t)row * N_DIM + col] = sat8(acc[mi][ni][r]);
            }
        }
    }
}

// ---- fallback (only if ws_size < 16MB): direct int32 GEMM, slow but correct ----
__global__ __launch_bounds__(256) void gemm_naive_kernel(const int* __restrict__ a,
                                                         const int* __restrict__ b,
                                                         int* __restrict__ C) {
    const int col = blockIdx.x * 256 + threadIdx.x;
    const int row = blockIdx.y;
    int acc = 0;
    for (int k = 0; k < K_DIM; ++k)
        acc += a[(size_t)row * K_DIM + k] * b[(size_t)k * N_DIM + col];
    C[(size_t)row * N_DIM + col] = sat8(acc);
}

extern "C" void kernel_launch(void* const* d_in, const int* in_sizes, int n_in,
                              void* d_out, int out_size, void* d_ws, size_t ws_size,
                              hipStream_t stream) {
    const int* a = (const int*)d_in[0];
    const int* b = (const int*)d_in[1];
    // alpha_row (d_in[2]) / alpha_col (d_in[3]) are unused in this variant.
    int* out = (int*)d_out;

    const size_t needed = 2 * (size_t)M_DIM * K_DIM;   // 16 MB packed operands
    if (ws_size < needed) {
        gemm_naive_kernel<<<dim3(N_DIM / 256, M_DIM), 256, 0, stream>>>(a, b, out);
        return;
    }

    char* A8 = (char*)d_ws;                          // 8 MB
    char* B8 = A8 + (size_t)M_DIM * K_DIM;           // 8 MB

    pack_ab_kernel<<<8192 + 2048, 256, 0, stream>>>(a, b, (int*)A8, B8);
    gemm_i8_kernel<<<dim3(N_DIM / 128, M_DIM / 128), 256, 0, stream>>>(A8, B8, out);
}

// Round 4
// 363.752 us; speedup vs baseline: 1.0249x; 1.0249x over previous
//
#include <hip/hip_runtime.h>
#include <stdint.h>

#define M_DIM 8192
#define N_DIM 8192
#define K_DIM 1024
#define BK    128

typedef int int4v  __attribute__((ext_vector_type(4)));
typedef int int16v __attribute__((ext_vector_type(16)));

// ---- async global->LDS, 16B per lane ----
__device__ __forceinline__ void gload16(const char* g, char* l) {
    __builtin_amdgcn_global_load_lds(
        (__attribute__((address_space(1))) void*)(void*)const_cast<char*>(g),
        (__attribute__((address_space(3))) void*)l,
        16, 0, 0);
}

__device__ __forceinline__ int sat8(int v) {
    v = v > 127 ? 127 : v;
    v = v < -128 ? -128 : v;
    return v;
}

// ---- fused pack: blocks [0,8192) pack A; blocks [8192,10240) transpose-pack B ----
__global__ __launch_bounds__(256) void pack_ab_kernel(const int* __restrict__ a,
                                                      const int* __restrict__ b,
                                                      int* __restrict__ outA,
                                                      char* __restrict__ outB) {
    __shared__ char tile[64][68];               // used by B-blocks only
    const int t = threadIdx.x;
    if (blockIdx.x < 8192) {
        // pack a: int32 [M][K] -> int8 [M][K], 4 elems/thread, coalesced
        int i = blockIdx.x * 256 + t;
        int4 v = ((const int4*)a)[i];
        outA[i] = (v.x & 0xff) | ((v.y & 0xff) << 8) |
                  ((v.z & 0xff) << 16) | ((v.w & 0xff) << 24);
        return;
    }
    // pack b: int32 [K][N] -> int8 [N][K] (transpose via LDS tile)
    const int bx = blockIdx.x - 8192;           // 0..2047
    const int n0 = (bx & 127) * 64;
    const int k0 = (bx >> 7) * 64;
    const int tr  = t >> 4;                     // 0..15
    const int tc4 = (t & 15) << 2;              // 0,4,..,60
#pragma unroll
    for (int j = 0; j < 4; ++j) {
        int row = tr + j * 16;                  // k within tile
        int4 v = *(const int4*)&b[(size_t)(k0 + row) * N_DIM + n0 + tc4];
        tile[row][tc4 + 0] = (char)v.x;
        tile[row][tc4 + 1] = (char)v.y;
        tile[row][tc4 + 2] = (char)v.z;
        tile[row][tc4 + 3] = (char)v.w;
    }
    __syncthreads();
#pragma unroll
    for (int j = 0; j < 4; ++j) {
        int n = tr + j * 16;                    // n within tile
        int pk = (tile[tc4 + 0][n] & 0xff) |
                 ((tile[tc4 + 1][n] & 0xff) << 8) |
                 ((tile[tc4 + 2][n] & 0xff) << 16) |
                 ((tile[tc4 + 3][n] & 0xff) << 24);
        *(int*)&outB[(size_t)(n0 + n) * K_DIM + k0 + tc4] = pk;
    }
}

// ---- GEMM: 128x128 tile, BK=128, 4 waves, 32x32x32 i8 MFMA, 4 blocks/CU ----
// R3 post-mortem: schedule variants (2-phase / 8-phase / 3-slot ring) all land
// 363-397us -> not schedule-bound. All pipes ~25% busy -> latency-bound at
// 12 waves/CU. This round: (1) __launch_bounds__(256,4) caps VGPR at 128 ->
// 4 blocks/CU (LDS 4x32KB=128<=160KiB), 16 waves/CU; (2) mfma_i32_32x32x32_i8
// halves MFMA instruction count at +12% pipe ceiling (4404 vs 3944 TOPS).
// Fragment mapping (derived from the verified 16x16x64 pattern, M<->K scale):
//   A: lane holds row lane&31, k-bytes (lane>>5)*16; B symmetric ([N][K] rows).
//   C/D: col=lane&31, row=(reg&3)+8*(reg>>2)+4*(lane>>5)  (m74/m101).
// Read-slot swizzle re-derived for 32-row frags: slot=(2*sl+hi)^((lane>>1)&3);
// 16B-chunk bank-position histogram is uniform (8 per position) -> conflict-
// free. Staging-side swizzle unchanged (rule 21: same store permutation).
__global__ __launch_bounds__(256, 4) void gemm_i8_kernel(const char* __restrict__ A8,
                                                         const char* __restrict__ B8,
                                                         int* __restrict__ C) {
    __shared__ __align__(16) char As[2 * 128 * 64];   // [k64-half][m][64B]
    __shared__ __align__(16) char Bs[2 * 128 * 64];   // [k64-half][n][64B]

    const int t    = threadIdx.x;
    const int bn   = blockIdx.x;
    const int bm   = blockIdx.y;
    const int lane = t & 63;
    const int wave = t >> 6;
    const int wm   = wave >> 1;                  // 2x2 wave grid, 64x64 per wave
    const int wn   = wave & 1;
    const int l31  = lane & 31;
    const int hi   = lane >> 5;
    const int lswz = (lane >> 1) & 3;            // == ((row>>1)&3) for all frags

    const size_t aBase = (size_t)(bm * 128) * K_DIM;
    const size_t bBase = (size_t)(bn * 128) * K_DIM;

    // staging (unchanged from verified R2): source chunk (t&3)^((t>>3)&3),
    // LDS dest linear -> stored slot s of row r holds global chunk s^((r>>1)&3)
    const int sr   = t >> 2;                     // row within 64-row half
    const int swzc = (((t & 3) ^ ((t >> 3) & 3)) << 4);

    // fragment read byte-offsets: row base + swizzled 16B slot
    const int aOff = (wm * 64 + l31) * 64;       // A row byte offset within half
    const int bOff = (wn * 64 + l31) * 64;
    const int slot0 = ((0 + hi) ^ lswz) << 4;    // k-slice 0 (k-bytes 0..31)
    const int slot1 = ((2 + hi) ^ lswz) << 4;    // k-slice 1 (k-bytes 32..63)

    int16v acc[2][2] = {};

    for (int kt = 0; kt < K_DIM / BK; ++kt) {
        const int kOff = kt * BK;
#pragma unroll
        for (int s = 0; s < 4; ++s) {
            const int p = s >> 1;                // K64-half
            const int rr = ((s & 1) << 6) + sr;  // tile row
            const int f = s * 4096 + t * 16;     // LDS flat offset (linear dest)
            gload16(A8 + aBase + (size_t)rr * K_DIM + kOff + p * 64 + swzc, As + f);
            gload16(B8 + bBase + (size_t)rr * K_DIM + kOff + p * 64 + swzc, Bs + f);
        }
        __syncthreads();   // drains vmcnt -> staged data visible

#pragma unroll
        for (int h = 0; h < 2; ++h) {            // two K64-halves per stage
#pragma unroll
            for (int sl = 0; sl < 2; ++sl) {     // two K32-slices per half
                const int sb = (sl == 0) ? slot0 : slot1;
                int4v a0 = *(const int4v*)&As[h * 8192 + aOff +    0 + sb];
                int4v a1 = *(const int4v*)&As[h * 8192 + aOff + 2048 + sb];
                int4v b0 = *(const int4v*)&Bs[h * 8192 + bOff +    0 + sb];
                int4v b1 = *(const int4v*)&Bs[h * 8192 + bOff + 2048 + sb];
                acc[0][0] = __builtin_amdgcn_mfma_i32_32x32x32_i8(a0, b0, acc[0][0], 0, 0, 0);
                acc[0][1] = __builtin_amdgcn_mfma_i32_32x32x32_i8(a0, b1, acc[0][1], 0, 0, 0);
                acc[1][0] = __builtin_amdgcn_mfma_i32_32x32x32_i8(a1, b0, acc[1][0], 0, 0, 0);
                acc[1][1] = __builtin_amdgcn_mfma_i32_32x32x32_i8(a1, b1, acc[1][1], 0, 0, 0);
            }
        }

        __syncthreads();   // LDS reads done before next stage overwrites
    }

    // epilogue: C/D col=lane&31, row=(reg&3)+8*(reg>>2)+4*hi; saturate, int32.
    // Per store: 32 consecutive ints x2 row-groups = 2x128B full-line segments.
    const int mBase = bm * 128 + wm * 64;
    const int nBase = bn * 128 + wn * 64;
#pragma unroll
    for (int mi = 0; mi < 2; ++mi) {
#pragma unroll
        for (int ni = 0; ni < 2; ++ni) {
            const int col = nBase + ni * 32 + l31;
#pragma unroll
            for (int r = 0; r < 16; ++r) {
                const int row = mBase + mi * 32 + (r & 3) + 8 * (r >> 2) + 4 * hi;
                C[(size_t)row * N_DIM + col] = sat8(acc[mi][ni][r]);
            }
        }
    }
}

// ---- fallback (only if ws_size < 16MB): direct int32 GEMM, slow but correct ----
__global__ __launch_bounds__(256) void gemm_naive_kernel(const int* __restrict__ a,
                                                         const int* __restrict__ b,
                                                         int* __restrict__ C) {
    const int col = blockIdx.x * 256 + threadIdx.x;
    const int row = blockIdx.y;
    int acc = 0;
    for (int k = 0; k < K_DIM; ++k)
        acc += a[(size_t)row * K_DIM + k] * b[(size_t)k * N_DIM + col];
    C[(size_t)row * N_DIM + col] = sat8(acc);
}

extern "C" void kernel_launch(void* const* d_in, const int* in_sizes, int n_in,
                              void* d_out, int out_size, void* d_ws, size_t ws_size,
                              hipStream_t stream) {
    const int* a = (const int*)d_in[0];
    const int* b = (const int*)d_in[1];
    // alpha_row (d_in[2]) / alpha_col (d_in[3]) are unused in this variant.
    int* out = (int*)d_out;

    const size_t needed = 2 * (size_t)M_DIM * K_DIM;   // 16 MB packed operands
    if (ws_size < needed) {
        gemm_naive_kernel<<<dim3(N_DIM / 256, M_DIM), 256, 0, stream>>>(a, b, out);
        return;
    }

    char* A8 = (char*)d_ws;                          // 8 MB
    char* B8 = A8 + (size_t)M_DIM * K_DIM;           // 8 MB

    pack_ab_kernel<<<8192 + 2048, 256, 0, stream>>>(a, b, (int*)A8, B8);
    gemm_i8_kernel<<<dim3(N_DIM / 128, M_DIM / 128), 256, 0, stream>>>(A8, B8, out);
}